// Round 4
// baseline (508.025 us; speedup 1.0000x reference)
//
#include <hip/hip_runtime.h>
#include <math.h>

#define EMBED 1024
#define HIDDEN 128
#define NPROTO 512

typedef short bf16x8 __attribute__((ext_vector_type(8)));
typedef float f32x4 __attribute__((ext_vector_type(4)));
typedef unsigned int u32x4 __attribute__((ext_vector_type(4)));

// round-half-up bf16 (0.5 ulp max, same as RNE except ties)
__device__ __forceinline__ unsigned short f2bf(float x) {
    unsigned u = __builtin_bit_cast(unsigned, x);
    return (unsigned short)((u + 0x8000u) >> 16);
}
__device__ __forceinline__ unsigned pk2(float a, float b) {
    unsigned ua = __builtin_bit_cast(unsigned, a) + 0x8000u;
    unsigned ub = __builtin_bit_cast(unsigned, b) + 0x8000u;
    return (ua >> 16) | (ub & 0xFFFF0000u);
}

#define GLL16(gptr, lptr)                                                \
    __builtin_amdgcn_global_load_lds(                                    \
        (const __attribute__((address_space(1))) void*)(gptr),           \
        (__attribute__((address_space(3))) void*)(lptr), 16, 0, 0)

// Prep: blocks 0..511   -> proto_h[b]  (fp32 GEMV, 2-way K-split)
//       blocks 512..575 -> w1t = bf16(W1[0:1024])^T, [n][k] layout
__global__ __launch_bounds__(256) void prep_kernel(
    const float* __restrict__ prototypes,   // [512][1024]
    const float* __restrict__ W1,           // [2048][128]
    float* __restrict__ proto_h,            // ws [512][128]
    unsigned short* __restrict__ w1t)       // ws [128][1024] bf16
{
    int b = blockIdx.x;
    int t = threadIdx.x;
    if (b < 512) {
        __shared__ float s_part[128];
        int ks = t >> 7, h = t & 127;
        const float* pr = prototypes + (size_t)b * EMBED + ks * 512;
        const float* w  = W1 + (size_t)(EMBED + ks * 512) * HIDDEN + h;
        float acc = 0.f;
        for (int k = 0; k < 512; k += 8) {
            #pragma unroll
            for (int j = 0; j < 8; ++j)
                acc += pr[k + j] * w[(size_t)(k + j) * HIDDEN];
        }
        if (ks) s_part[h] = acc;
        __syncthreads();
        if (!ks) proto_h[(size_t)b * HIDDEN + h] = acc + s_part[h];
    } else {
        int s = (b - 512) * 256 + t;        // 0..16383
        int n = s & 127;
        int k0 = (s >> 7) * 8;              // 0..1016
        bf16x8 v;
        #pragma unroll
        for (int j = 0; j < 8; ++j)
            v[j] = (short)f2bf(W1[(size_t)(k0 + j) * HIDDEN + n]);
        *(bf16x8*)(w1t + (size_t)n * EMBED + k0) = v;
    }
}

// Fused: argmin -> MFMA GEMM -> +proto_h[idx]+b1 -> relu -> dot W2 -> sigmoid.
//  * ALL qf traffic row-contiguous: each global_load_lds covers two full 512B
//    row-chunks (contiguity hypothesis: 32B-granule scatter caps ~1.5 TB/s).
//  * W1 fully VGPR-resident per wave (16-hidden slice x K=1024 = 128 VGPR),
//    loaded by compiler BEFORE the staging glls -> oldest in vmcnt queue ->
//    compiler's wait for B never drains the gll pipeline. No mid-loop reload.
//  * Loop contains ONLY gll vmem ops -> exact hand vmcnt ledger, WAITB(4)/stage.
// Block: 512 thr / 8 waves / 64 query rows. Wave w: all 64 rows x hidden
// [w*16, w*16+16). LDS: A dbuf 2x32KB (64 rows x 128 f32 cols, XOR-swizzled).
__global__ __launch_bounds__(512, 2) void main_kernel(
    const float* __restrict__ qf,           // [65536][1024]
    const float* __restrict__ dist,         // [65536][512]
    const float* __restrict__ b1,           // [128]
    const float* __restrict__ W2,           // [128]
    const float* __restrict__ b2,           // [1]
    const float* __restrict__ proto_h,      // [512][128]
    const unsigned short* __restrict__ w1t, // [128][1024] bf16
    float* __restrict__ out)                // [65536]
{
    __shared__ __align__(16) char lds_a[2][32768];
    __shared__ int s_idx[64];
    __shared__ float s_red[64][8];

    const int t = threadIdx.x;
    const int wave = t >> 6, lane = t & 63;
    const int quad = lane >> 4, tid16 = lane & 15;
    const int q0 = blockIdx.x * 64;

    // ---- W1 slice resident (issued FIRST -> oldest in vmcnt queue) ----
    bf16x8 B[32];
    {
        const unsigned short* wb = w1t + (size_t)(wave * 16 + tid16) * EMBED + quad * 8;
        #pragma unroll
        for (int ks = 0; ks < 32; ++ks)
            B[ks] = *(const bf16x8*)(wb + ks * 32);
    }

    // ---- gll source pointers: wave w stages rows w*8..w*8+7, 4 glls of 1KB.
    // LDS row r lives at r*512 within the buffer; byte b of row r holds qf
    // col-byte (b ^ swz_r), swz_r = ((r&3)<<5) | (((r>>3)&1)<<4)  (source-side
    // swizzle; gll dest must stay linear -- rule 21).
    const char* gsrc[4];
    {
        int rl = wave * 8 + (lane >> 5);               // + 2i per gll
        int j16 = (lane & 31) * 16;
        #pragma unroll
        for (int i = 0; i < 4; ++i) {
            int r = rl + 2 * i;
            int swz = ((r & 3) << 5) | (((r >> 3) & 1) << 4);
            gsrc[i] = (const char*)qf + (size_t)(q0 + r) * 4096 + (j16 ^ swz);
        }
    }

#define STAGE(s) do {                                                    \
        char* lb_ = &lds_a[(s) & 1][wave * 4096];                        \
        _Pragma("unroll")                                                \
        for (int i_ = 0; i_ < 4; ++i_)                                   \
            GLL16(gsrc[i_] + (s) * 512, lb_ + i_ * 1024);                \
    } while (0)

    // ---- Prologue: stages 0,1 in flight during argmin ----
    STAGE(0);
    STAGE(1);

    // ---- Phase 1: argmin, 8 rows per wave (contiguous 1KB dist reads) ----
    {
        const int q0w = q0 + wave * 8;
        for (int i = 0; i < 8; i += 4) {
            float4 v0[4], v1[4];
            #pragma unroll
            for (int j = 0; j < 4; ++j) {
                const float* dr = dist + (size_t)(q0w + i + j) * NPROTO;
                v0[j] = ((const float4*)dr)[lane];
                v1[j] = ((const float4*)dr)[lane + 64];
            }
            #pragma unroll
            for (int j = 0; j < 4; ++j) {
                float bv = v0[j].x; int bi = lane * 4;
                if (v0[j].y < bv) { bv = v0[j].y; bi = lane * 4 + 1; }
                if (v0[j].z < bv) { bv = v0[j].z; bi = lane * 4 + 2; }
                if (v0[j].w < bv) { bv = v0[j].w; bi = lane * 4 + 3; }
                int c = 256 + lane * 4;
                if (v1[j].x < bv) { bv = v1[j].x; bi = c; }
                if (v1[j].y < bv) { bv = v1[j].y; bi = c + 1; }
                if (v1[j].z < bv) { bv = v1[j].z; bi = c + 2; }
                if (v1[j].w < bv) { bv = v1[j].w; bi = c + 3; }
                #pragma unroll
                for (int s = 1; s < 64; s <<= 1) {
                    float ov = __shfl_xor(bv, s);
                    int   oi = __shfl_xor(bi, s);
                    if (ov < bv || (ov == bv && oi < bi)) { bv = ov; bi = oi; }
                }
                if (lane == 0) s_idx[wave * 8 + i + j] = bi;
            }
        }
    }

    // ---- Phase 2: 8 stages x 128 f32 cols, dbuf, counted vmcnt ----
    f32x4 acc[4];
    #pragma unroll
    for (int mi = 0; mi < 4; ++mi)
        acc[mi] = (f32x4){0.f, 0.f, 0.f, 0.f};

    // fragment base: row m = mi*16+tid16, colbyte kk*128 + quad*32, XOR-swizzled
    const int abase = tid16 * 512 + ((quad * 32) ^ ((tid16 & 3) << 5))
                    + (((tid16 >> 3) & 1) << 4);

#define WAITB(N) do {                                                    \
        asm volatile("s_waitcnt vmcnt(" #N ")\n\ts_barrier" ::: "memory"); \
        __builtin_amdgcn_sched_barrier(0);                               \
    } while (0)
#define BAR() __builtin_amdgcn_s_barrier()

#define COMPUTE(s) do {                                                  \
        const char* La = lds_a[(s) & 1];                                 \
        _Pragma("unroll")                                                \
        for (int kk = 0; kk < 4; ++kk) {                                 \
            _Pragma("unroll")                                            \
            for (int mi = 0; mi < 4; ++mi) {                             \
                int o = abase + mi * 8192 + kk * 128;                    \
                float4 lo = *(const float4*)(La + o);                    \
                float4 hi = *(const float4*)(La + (o ^ 16));             \
                u32x4 p_;                                                \
                p_.x = pk2(lo.x, lo.y); p_.y = pk2(lo.z, lo.w);          \
                p_.z = pk2(hi.x, hi.y); p_.w = pk2(hi.z, hi.w);          \
                bf16x8 af = __builtin_bit_cast(bf16x8, p_);              \
                acc[mi] = __builtin_amdgcn_mfma_f32_16x16x32_bf16(       \
                    af, B[(s) * 4 + kk], acc[mi], 0, 0, 0);              \
            }                                                            \
        }                                                                \
    } while (0)

    // Ledger (per wave, 4 glls/stage; outstanding sets tabulated):
    // entering loop worst case {st0,st1}=8.
    WAITB(4); COMPUTE(0); BAR(); STAGE(2);   // {st1,st2}
    WAITB(4); COMPUTE(1); BAR(); STAGE(3);   // {st2,st3}
    WAITB(4); COMPUTE(2); BAR(); STAGE(4);   // {st3,st4}
    WAITB(4); COMPUTE(3); BAR(); STAGE(5);   // {st4,st5}
    WAITB(4); COMPUTE(4); BAR(); STAGE(6);   // {st5,st6}
    WAITB(4); COMPUTE(5); BAR(); STAGE(7);   // {st6,st7}
    WAITB(4); COMPUTE(6);                    // {st7}
    WAITB(0); COMPUTE(7);                    // {}

    // ---- Epilogue: +b1 +proto_h[idx], relu, * W2 (1 col/lane), reduce ----
    const int n = wave * 16 + tid16;
    const float b1v = b1[n];
    const float w2v = W2[n];
    #pragma unroll
    for (int mi = 0; mi < 4; ++mi) {
        #pragma unroll
        for (int r = 0; r < 4; ++r) {
            int m = mi * 16 + quad * 4 + r;
            float v = acc[mi][r] + b1v + proto_h[(size_t)s_idx[m] * HIDDEN + n];
            float sum = fmaxf(v, 0.f) * w2v;
            #pragma unroll
            for (int s = 1; s < 16; s <<= 1) sum += __shfl_xor(sum, s);
            if (tid16 == 0) s_red[m][wave] = sum;
        }
    }
    __syncthreads();
    if (t < 64) {
        float s = s_red[t][0] + s_red[t][1] + s_red[t][2] + s_red[t][3]
                + s_red[t][4] + s_red[t][5] + s_red[t][6] + s_red[t][7] + b2[0];
        out[q0 + t] = 1.f / (1.f + expf(-s));
    }
#undef STAGE
#undef WAITB
#undef BAR
#undef COMPUTE
}

extern "C" void kernel_launch(void* const* d_in, const int* in_sizes, int n_in,
                              void* d_out, int out_size, void* d_ws, size_t ws_size,
                              hipStream_t stream) {
    const float* qf    = (const float*)d_in[0];   // [65536,1024]
    const float* proto = (const float*)d_in[1];   // [512,1024]
    const float* dist  = (const float*)d_in[2];   // [65536,512]
    const float* W1    = (const float*)d_in[3];   // [2048,128]
    const float* b1    = (const float*)d_in[4];   // [128]
    const float* W2    = (const float*)d_in[5];   // [128,1]
    const float* b2    = (const float*)d_in[6];   // [1]
    float* out = (float*)d_out;

    float* proto_h = (float*)d_ws;                                        // 256 KB
    unsigned short* w1t = (unsigned short*)((char*)d_ws + 512 * 128 * 4); // 256 KB

    prep_kernel<<<576, 256, 0, stream>>>(proto, W1, proto_h, w1t);

    int nq = in_sizes[0] / EMBED;  // 65536
    main_kernel<<<nq / 64, 512, 0, stream>>>(qf, dist, b1, W2, b2, proto_h, w1t, out);
}

// Round 5
// 484.593 us; speedup vs baseline: 1.0484x; 1.0484x over previous
//
#include <hip/hip_runtime.h>
#include <math.h>

#define EMBED 1024
#define HIDDEN 128
#define NPROTO 512

typedef short bf16x8 __attribute__((ext_vector_type(8)));
typedef float f32x4 __attribute__((ext_vector_type(4)));
typedef unsigned int u32x4 __attribute__((ext_vector_type(4)));

// round-half-up bf16 (0.5 ulp max, same as RNE except ties)
__device__ __forceinline__ unsigned short f2bf(float x) {
    unsigned u = __builtin_bit_cast(unsigned, x);
    return (unsigned short)((u + 0x8000u) >> 16);
}
__device__ __forceinline__ unsigned pk2(float a, float b) {
    unsigned ua = __builtin_bit_cast(unsigned, a) + 0x8000u;
    unsigned ub = __builtin_bit_cast(unsigned, b) + 0x8000u;
    return (ua >> 16) | (ub & 0xFFFF0000u);
}

#define GLL16(gptr, lptr)                                                \
    __builtin_amdgcn_global_load_lds(                                    \
        (const __attribute__((address_space(1))) void*)(gptr),           \
        (__attribute__((address_space(3))) void*)(lptr), 16, 0, 0)

// Prep: blocks 0..511   -> proto_h[b]  (fp32 GEMV, 2-way K-split)
//       blocks 512..575 -> w1t = bf16(W1[0:1024])^T, [n][k] layout
__global__ __launch_bounds__(256) void prep_kernel(
    const float* __restrict__ prototypes,   // [512][1024]
    const float* __restrict__ W1,           // [2048][128]
    float* __restrict__ proto_h,            // ws [512][128]
    unsigned short* __restrict__ w1t)       // ws [128][1024] bf16
{
    int b = blockIdx.x;
    int t = threadIdx.x;
    if (b < 512) {
        __shared__ float s_part[128];
        int ks = t >> 7, h = t & 127;
        const float* pr = prototypes + (size_t)b * EMBED + ks * 512;
        const float* w  = W1 + (size_t)(EMBED + ks * 512) * HIDDEN + h;
        float acc = 0.f;
        for (int k = 0; k < 512; k += 8) {
            #pragma unroll
            for (int j = 0; j < 8; ++j)
                acc += pr[k + j] * w[(size_t)(k + j) * HIDDEN];
        }
        if (ks) s_part[h] = acc;
        __syncthreads();
        if (!ks) proto_h[(size_t)b * HIDDEN + h] = acc + s_part[h];
    } else {
        int s = (b - 512) * 256 + t;        // 0..16383
        int n = s & 127;
        int k0 = (s >> 7) * 8;              // 0..1016
        bf16x8 v;
        #pragma unroll
        for (int j = 0; j < 8; ++j)
            v[j] = (short)f2bf(W1[(size_t)(k0 + j) * HIDDEN + n]);
        *(bf16x8*)(w1t + (size_t)n * EMBED + k0) = v;
    }
}

// Fused: argmin -> MFMA GEMM -> +proto_h[idx]+b1 -> relu -> dot W2 -> sigmoid.
// Design (round-5 diagnosis: prior rounds were LDS/VALU-serialization-bound):
//  * A NEVER touches LDS: wave owns its 32 rows exclusively; A frags load
//    f32 global->VGPR (depth-2 rotation), converted to bf16 exactly once.
//    No cross-wave A sharing -> no 8x LDS read amplification, no redundant cvt.
//  * B staged via global_load_lds, 128-k chunks (32KB, dbuf), prefetch
//    distance 1 chunk, one __syncthreads per chunk (8 total) -> gll->ds_read
//    visibility correct by construction.
//  * B LDS layout XOR-swizzled by ((n&7)<<4) on the gll SOURCE; read applies
//    the same XOR -> 64 lanes spread exactly 8-per-16B-slot = conflict-free.
// Block: 256 thr / 4 waves; tile M=128 (wave w: rows 32w..32w+31, m_rep=2),
// N=128 (n_rep=8). Grid 512 -> 2 blocks/CU (LDS 66KB, VGPR <= 256).
__global__ __launch_bounds__(256, 2) void main_kernel(
    const float* __restrict__ qf,           // [65536][1024]
    const float* __restrict__ dist,         // [65536][512]
    const float* __restrict__ b1,           // [128]
    const float* __restrict__ W2,           // [128]
    const float* __restrict__ b2,           // [1]
    const float* __restrict__ proto_h,      // [512][128]
    const unsigned short* __restrict__ w1t, // [128][1024] bf16
    float* __restrict__ out)                // [65536]
{
    __shared__ __align__(16) char lds_b[2][32768];
    __shared__ int s_idx[4][32];

    const int t = threadIdx.x;
    const int wave = t >> 6, lane = t & 63;
    const int quad = lane >> 4, tid16 = lane & 15;
    const int q0  = blockIdx.x * 128;
    const int q0w = q0 + wave * 32;

    // ---- B gll source lane offsets (swizzle on SOURCE, LDS dest linear) ----
    // gll g covers n in [32*wave + 4g, +4); lane l: n_off = l>>4, kb=(l&15)*16.
    // stored_lds[n*256 + kb] = w1t_row_n[c*256 + (kb ^ ((n&7)<<4))]
    const int ln = lane >> 4, lk = (lane & 15) * 16;
    const size_t off_e = (size_t)ln * 2048 + (lk ^ (ln << 4));          // g even: n&7=ln
    const size_t off_o = (size_t)ln * 2048 + (lk ^ (((4 + ln) & 7) << 4)); // g odd
    const char* wsrc = (const char*)w1t + (size_t)wave * 65536;

#define STAGE_B(c, buf) do {                                             \
        char* lb_ = &lds_b[buf][wave * 8192];                            \
        _Pragma("unroll")                                                \
        for (int g_ = 0; g_ < 8; ++g_)                                   \
            GLL16(wsrc + g_ * 8192 + (c) * 256 + ((g_ & 1) ? off_o : off_e), \
                  lb_ + g_ * 1024);                                      \
    } while (0)

    // ---- A addressing: lane reads row q0w + mi*16 + tid16, k = s*32+quad*8 ----
    const float* abase = qf + (size_t)(q0w + tid16) * EMBED + quad * 8;

#define LOADA(dst, s) do {                                               \
        _Pragma("unroll")                                                \
        for (int mi_ = 0; mi_ < 2; ++mi_) {                              \
            const float* p_ = abase + (size_t)(mi_ * 16) * EMBED + (s) * 32; \
            dst[mi_][0] = ((const float4*)p_)[0];                        \
            dst[mi_][1] = ((const float4*)p_)[1];                        \
        }                                                                \
    } while (0)

#define CVT(af, src) do {                                                \
        _Pragma("unroll")                                                \
        for (int mi_ = 0; mi_ < 2; ++mi_) {                              \
            u32x4 p_;                                                    \
            p_.x = pk2(src[mi_][0].x, src[mi_][0].y);                    \
            p_.y = pk2(src[mi_][0].z, src[mi_][0].w);                    \
            p_.z = pk2(src[mi_][1].x, src[mi_][1].y);                    \
            p_.w = pk2(src[mi_][1].z, src[mi_][1].w);                    \
            af[mi_] = __builtin_bit_cast(bf16x8, p_);                    \
        }                                                                \
    } while (0)

    // ---- Prologue: B chunk 0 + A steps 0,1 in flight during argmin ----
    STAGE_B(0, 0);
    float4 a0[2][2], a1[2][2];
    LOADA(a0, 0);
    LOADA(a1, 1);

    // ---- Phase 1: argmin over 512 distances, 32 rows per wave ----
    for (int i = 0; i < 32; i += 4) {
        float4 v0[4], v1[4];
        #pragma unroll
        for (int j = 0; j < 4; ++j) {
            const float* dr = dist + (size_t)(q0w + i + j) * NPROTO;
            v0[j] = ((const float4*)dr)[lane];
            v1[j] = ((const float4*)dr)[lane + 64];
        }
        #pragma unroll
        for (int j = 0; j < 4; ++j) {
            float bv = v0[j].x; int bi = lane * 4;
            if (v0[j].y < bv) { bv = v0[j].y; bi = lane * 4 + 1; }
            if (v0[j].z < bv) { bv = v0[j].z; bi = lane * 4 + 2; }
            if (v0[j].w < bv) { bv = v0[j].w; bi = lane * 4 + 3; }
            int c = 256 + lane * 4;
            if (v1[j].x < bv) { bv = v1[j].x; bi = c; }
            if (v1[j].y < bv) { bv = v1[j].y; bi = c + 1; }
            if (v1[j].z < bv) { bv = v1[j].z; bi = c + 2; }
            if (v1[j].w < bv) { bv = v1[j].w; bi = c + 3; }
            #pragma unroll
            for (int s = 1; s < 64; s <<= 1) {
                float ov = __shfl_xor(bv, s);
                int   oi = __shfl_xor(bi, s);
                if (ov < bv || (ov == bv && oi < bi)) { bv = ov; bi = oi; }
            }
            if (lane == 0) s_idx[wave][i + j] = bi;
        }
    }

    // ---- Phase 2: GEMM, 8 chunks x 4 k-steps (k-step = 32) ----
    f32x4 acc[2][8];
    #pragma unroll
    for (int mi = 0; mi < 2; ++mi)
        #pragma unroll
        for (int ni = 0; ni < 8; ++ni)
            acc[mi][ni] = (f32x4){0.f, 0.f, 0.f, 0.f};

    // B frag read base (inverse swizzle; bank-uniform 8 lanes/slot):
    // addr = ni*4096 + tid16*256 + ((quad^(tid16&3))<<4)
    //        + (((s&1)^((tid16>>2)&1))<<6) + ((s>>1)&1)*128
    const int Lb = tid16 * 256 + ((quad ^ (tid16 & 3)) << 4)
                 + (((tid16 >> 2) & 1) << 6);

#define STEP(s, buf) do {                                                \
        bf16x8 af[2];                                                    \
        if ((s) & 1) { CVT(af, a1); if ((s) + 2 < 32) LOADA(a1, (s) + 2); } \
        else         { CVT(af, a0); if ((s) + 2 < 32) LOADA(a0, (s) + 2); } \
        const char* pb = &lds_b[buf][(Lb ^ (((s) & 1) << 6))             \
                                     + (((s) >> 1) & 1) * 128];          \
        bf16x8 bfr[8];                                                   \
        _Pragma("unroll")                                                \
        for (int ni_ = 0; ni_ < 8; ++ni_)                                \
            bfr[ni_] = *(const bf16x8*)(pb + ni_ * 4096);                \
        _Pragma("unroll")                                                \
        for (int mi_ = 0; mi_ < 2; ++mi_)                                \
            _Pragma("unroll")                                            \
            for (int ni_ = 0; ni_ < 8; ++ni_)                            \
                acc[mi_][ni_] = __builtin_amdgcn_mfma_f32_16x16x32_bf16( \
                    af[mi_], bfr[ni_], acc[mi_][ni_], 0, 0, 0);          \
    } while (0)

    #pragma unroll
    for (int c = 0; c < 8; ++c) {
        __syncthreads();                       // B chunk c staged & visible
        if (c < 7) STAGE_B(c + 1, (c + 1) & 1);
        STEP(c * 4 + 0, c & 1);
        STEP(c * 4 + 1, c & 1);
        STEP(c * 4 + 2, c & 1);
        STEP(c * 4 + 3, c & 1);
    }

    // ---- Epilogue (wave-local): +b1 +proto_h[idx], relu, dot W2, sigmoid ----
    float b1v[8], w2v[8];
    #pragma unroll
    for (int ni = 0; ni < 8; ++ni) {
        b1v[ni] = b1[ni * 16 + tid16];
        w2v[ni] = W2[ni * 16 + tid16];
    }
    const float b2v = b2[0];
    #pragma unroll
    for (int mi = 0; mi < 2; ++mi) {
        #pragma unroll
        for (int r = 0; r < 4; ++r) {
            int m = mi * 16 + quad * 4 + r;
            const float* ph = proto_h + (size_t)s_idx[wave][m] * HIDDEN + tid16;
            float sum = 0.f;
            #pragma unroll
            for (int ni = 0; ni < 8; ++ni) {
                float v = acc[mi][ni][r] + b1v[ni] + ph[ni * 16];
                sum += fmaxf(v, 0.f) * w2v[ni];
            }
            #pragma unroll
            for (int s = 1; s < 16; s <<= 1) sum += __shfl_xor(sum, s);
            if (tid16 == 0) out[q0w + m] = 1.f / (1.f + expf(-(sum + b2v)));
        }
    }
#undef STAGE_B
#undef LOADA
#undef CVT
#undef STEP
}

extern "C" void kernel_launch(void* const* d_in, const int* in_sizes, int n_in,
                              void* d_out, int out_size, void* d_ws, size_t ws_size,
                              hipStream_t stream) {
    const float* qf    = (const float*)d_in[0];   // [65536,1024]
    const float* proto = (const float*)d_in[1];   // [512,1024]
    const float* dist  = (const float*)d_in[2];   // [65536,512]
    const float* W1    = (const float*)d_in[3];   // [2048,128]
    const float* b1    = (const float*)d_in[4];   // [128]
    const float* W2    = (const float*)d_in[5];   // [128,1]
    const float* b2    = (const float*)d_in[6];   // [1]
    float* out = (float*)d_out;

    float* proto_h = (float*)d_ws;                                        // 256 KB
    unsigned short* w1t = (unsigned short*)((char*)d_ws + 512 * 128 * 4); // 256 KB

    prep_kernel<<<576, 256, 0, stream>>>(proto, W1, proto_h, w1t);

    int nq = in_sizes[0] / EMBED;  // 65536
    main_kernel<<<nq / 128, 256, 0, stream>>>(qf, dist, b1, W2, b2, proto_h, w1t, out);
}